// Round 9
// baseline (360.693 us; speedup 1.0000x reference)
//
#include <hip/hip_runtime.h>

// Problem constants (T=64, B=32, I=128, H=256, alpha=0.2)
#define TT 64
#define BB 32
#define II 128
#define HH 256
#define MM (TT*BB)   // 2048

typedef __bf16  bf16x8  __attribute__((ext_vector_type(8)));
typedef float   f32x16  __attribute__((ext_vector_type(16)));
typedef _Float16 half2v __attribute__((ext_vector_type(2)));
typedef unsigned int u32;

__device__ __forceinline__ float bf2f(unsigned short u) {
    union { unsigned int i; float f; } v; v.i = ((unsigned int)u) << 16; return v.f;
}
__device__ __forceinline__ unsigned short f2bf(float f) {
    union { float f; unsigned int i; } v; v.f = f;
    unsigned int r = v.i + 0x7fffu + ((v.i >> 16) & 1u);
    return (unsigned short)(r >> 16);
}

// async 16B HBM->LDS copy, no destination VGPR. LDS base must be wave-uniform;
// hardware writes base + lane*16.
__device__ __forceinline__ void gload16(const unsigned short* g, unsigned short* l) {
    __builtin_amdgcn_global_load_lds(
        (const __attribute__((address_space(1))) u32*)g,
        (__attribute__((address_space(3))) u32*)l,
        16, 0, 0);
}

// Dual-dtype loaders: external tensors may be fp32 or bf16; runtime flag decides.
struct F8 { float v[8]; };
__device__ __forceinline__ F8 load8(const void* base, int idx, int isf32) {
    F8 r;
    if (isf32) {
        const float4* p = (const float4*)((const float*)base + idx);
        float4 a = p[0], b = p[1];
        r.v[0]=a.x; r.v[1]=a.y; r.v[2]=a.z; r.v[3]=a.w;
        r.v[4]=b.x; r.v[5]=b.y; r.v[6]=b.z; r.v[7]=b.w;
    } else {
        uint4 u = *(const uint4*)((const unsigned short*)base + idx);
        const unsigned short* p = (const unsigned short*)&u;
#pragma unroll
        for (int j = 0; j < 8; ++j) r.v[j] = bf2f(p[j]);
    }
    return r;
}
__device__ __forceinline__ float load1(const void* base, int idx, int isf32) {
    return isf32 ? ((const float*)base)[idx]
                 : bf2f(((const unsigned short*)base)[idx]);
}

__device__ __forceinline__ float fdot2f(half2v a, half2v b, float c) {
#if __has_builtin(__builtin_amdgcn_fdot2)
    return __builtin_amdgcn_fdot2(a, b, c, false);
#else
    return c + (float)a.x*(float)b.x + (float)a.y*(float)b.y;
#endif
}

// ---------------------------------------------------------------------------
// K0: dtype sniffer (fp32 read as ushorts -> ~25% have exponent >= 0xC0).
// ---------------------------------------------------------------------------
__global__ __launch_bounds__(256) void k0_sniff(
    const unsigned short* __restrict__ x, int* __restrict__ flag)
{
    __shared__ int cnt;
    if (threadIdx.x == 0) cnt = 0;
    __syncthreads();
    int c = 0;
    for (int i = threadIdx.x; i < 8192; i += 256) {
        unsigned int e = (x[i] >> 7) & 0xFFu;
        if (e >= 0xC0u) ++c;
    }
    atomicAdd(&cnt, c);
    __syncthreads();
    if (threadIdx.x == 0) flag[0] = (cnt > 16) ? 1 : 0;
}

// ---------------------------------------------------------------------------
// K1 (unchanged): emits ipT[j][m] via LDS transpose.
// ---------------------------------------------------------------------------
__global__ __launch_bounds__(256) void k1_proj(
    const void* __restrict__ x,
    const void* __restrict__ w_i2h,
    const void* __restrict__ b_i2h,
    const void* __restrict__ w_i2c,
    const void* __restrict__ b_i2c,
    const int* __restrict__ flagp,
    unsigned short* __restrict__ ipT,
    float* __restrict__ cin)
{
    const int isf32 = *flagp;
    const int tid = threadIdx.x;
    const int h = tid;
    const int mbase = blockIdx.x * 32;
    __shared__ __align__(16) _Float16 xs[32][II];          // 8 KB
    __shared__ __align__(16) unsigned short ips[32][HH];   // 16 KB

    half2v w1[II/2], w2[II/2];
#pragma unroll
    for (int c8 = 0; c8 < II/8; ++c8) {
        F8 f1 = load8(w_i2h, h*II + c8*8, isf32);
        F8 f2 = load8(w_i2c, h*II + c8*8, isf32);
#pragma unroll
        for (int j = 0; j < 4; ++j) {
            half2v a; a.x = (_Float16)f1.v[2*j]; a.y = (_Float16)f1.v[2*j+1];
            half2v b; b.x = (_Float16)f2.v[2*j]; b.y = (_Float16)f2.v[2*j+1];
            w1[c8*4 + j] = a;
            w2[c8*4 + j] = b;
        }
    }
    const float bb1 = load1(b_i2h, h, isf32);
    const float bb2 = load1(b_i2c, h, isf32);

    for (int u = tid; u < 32*II; u += 256)
        xs[u >> 7][u & (II-1)] = (_Float16)load1(x, (mbase + (u >> 7))*II + (u & (II-1)), isf32);
    __syncthreads();

    for (int mm = 0; mm < 32; ++mm) {
        const half2v* xv = (const half2v*)xs[mm];
        float a0=0,a1=0,a2=0,a3=0, c0=0,c1=0,c2=0,c3=0;
#pragma unroll
        for (int r = 0; r < II/2; r += 4) {
            half2v x0 = xv[r], x1 = xv[r+1], x2 = xv[r+2], x3 = xv[r+3];
            a0 = fdot2f(w1[r],   x0, a0);
            a1 = fdot2f(w1[r+1], x1, a1);
            a2 = fdot2f(w1[r+2], x2, a2);
            a3 = fdot2f(w1[r+3], x3, a3);
            c0 = fdot2f(w2[r],   x0, c0);
            c1 = fdot2f(w2[r+1], x1, c1);
            c2 = fdot2f(w2[r+2], x2, c2);
            c3 = fdot2f(w2[r+3], x3, c3);
        }
        ips[mm][h] = f2bf(((a0+a1)+(a2+a3)) + bb1);
        cin[(mbase+mm)*HH + h] = ((c0+c1)+(c2+c3)) + bb2;
    }
    __syncthreads();
    unsigned short tmp[32];
#pragma unroll
    for (int mm = 0; mm < 32; ++mm) tmp[mm] = ips[mm][tid];
    uint4* dst = (uint4*)(ipT + (size_t)tid*MM + mbase);
    const uint4* s4 = (const uint4*)tmp;
    dst[0] = s4[0]; dst[1] = s4[1]; dst[2] = s4[2]; dst[3] = s4[3];
}

// ---------------------------------------------------------------------------
// K2 (unchanged): per-sample context chains, double-buffered LDS.
// ---------------------------------------------------------------------------
__global__ __launch_bounds__(256) void k2_ctx(
    const void* __restrict__ w_c2c,
    const void* __restrict__ b_c2c,
    const float* __restrict__ cin,
    const int* __restrict__ ns_ptr,
    const int* __restrict__ flagp,
    unsigned short* __restrict__ ctx_hist,
    void* __restrict__ out_base)
{
    const int isf32 = *flagp;
    const int b = blockIdx.x;
    const int h = threadIdx.x;
    const int ns = max(1, *ns_ptr);

    __shared__ __align__(16) _Float16 cs[2][HH];

    half2v w[HH/2];
#pragma unroll
    for (int c8 = 0; c8 < HH/8; ++c8) {
        F8 f = load8(w_c2c, h*HH + c8*8, isf32);
#pragma unroll
        for (int j = 0; j < 4; ++j) {
            half2v hv;
            hv.x = (_Float16)f.v[2*j];
            hv.y = (_Float16)f.v[2*j+1];
            w[c8*4 + j] = hv;
        }
    }
    const float bcc = load1(b_c2c, h, isf32);
    float ctxv = 0.0f;
    cs[0][h] = (_Float16)0.0f;
    __syncthreads();
    int cur = 0;

    for (int t = 0; t < TT; ++t) {
        const float cinv = cin[(t*BB + b)*HH + h];
        for (int s = 0; s < ns; ++s) {
            if (s == ns-1) ctx_hist[(t*BB + b)*HH + h] = f2bf(ctxv);
            float p0=0,p1=0,p2=0,p3=0;
            const float4* cp4 = (const float4*)cs[cur];
#pragma unroll
            for (int r4 = 0; r4 < HH/8; ++r4) {
                float4 blob = cp4[r4];
                const half2v* c2 = (const half2v*)&blob;
                p0 = fdot2f(w[r4*4+0], c2[0], p0);
                p1 = fdot2f(w[r4*4+1], c2[1], p1);
                p2 = fdot2f(w[r4*4+2], c2[2], p2);
                p3 = fdot2f(w[r4*4+3], c2[3], p3);
            }
            float cnew = fmaxf(((p0+p1)+(p2+p3)) + bcc + cinv, 0.0f);
            ctxv = 0.8f*ctxv + 0.2f*cnew;
            cs[cur^1][h] = (_Float16)ctxv;
            cur ^= 1;
            __syncthreads();
        }
    }
    const int cofs = MM*HH + BB*HH + b*HH + h;
    if (isf32) ((float*)out_base)[cofs] = ctxv;
    else       ((unsigned short*)out_base)[cofs] = f2bf(ctxv);
}

// ---------------------------------------------------------------------------
// K25: zero outT (2 MB) before k3's atomic accumulation.
// ---------------------------------------------------------------------------
__global__ __launch_bounds__(256) void k25_zero(float* __restrict__ outT)
{
    const int idx = (blockIdx.x * 256 + threadIdx.x) * 4;
    *(float4*)(outT + idx) = make_float4(0.f, 0.f, 0.f, 0.f);
}

// ---------------------------------------------------------------------------
// K3 v11: v10's counted-vmcnt 8-phase pipeline with a FAT accumulator.
//  * acc[2][4] (128 AGPR): wave tile 64j x 128m; per ks: 2 W-reads + 4
//    ctx-reads -> 8 MFMAs (read:MFMA 0.75 vs v10's 1.0) and m-chunk = 512
//    -> 32 barrier-phases/block (v10: 64). 2 waves/SIMD => 256-reg budget;
//    total ~205 regs. Spill signature = FETCH/WRITE growth (v7 lesson).
//  * LDS 160 KB: Ws [32ku][128j] (64 KB, conflict-free) + ring 3 x 32 KB
//    ([4ku][512m] BK=32 chunks). Prefetch depth 2; vmcnt(4) phases 0-6,
//    vmcnt(0) phase 7 (drain before Ps overlay). Raw s_barrier per phase.
//  * bc folded into acc init; per-n lean epilogue; Ps (4 KB overlay on
//    ring[0]) + atomicAdd into outT (zeroed by k25) as in v9/v10.
// ---------------------------------------------------------------------------
__global__ __launch_bounds__(512, 2) void k3_main(
    const unsigned short* __restrict__ ctx_hist,  // [2048 m,256 k] bf16 (internal)
    const void* __restrict__ wc,                  // [65536,256] external
    const void* __restrict__ bc,                  // [65536]     external
    const unsigned short* __restrict__ ipT,       // [256 j][2048 m] bf16 (internal)
    const int* __restrict__ flagp,
    float* __restrict__ outT)                     // [256 i][2048 m] f32 (internal)
{
    extern __shared__ __align__(16) unsigned char lds[];
    unsigned short* Ws   = (unsigned short*)lds;             // 65536 B [ku][jrow]
    unsigned short* ring = (unsigned short*)(lds + 65536);   // 3 x 32768 B
    float*          Ps   = (float*)(lds + 65536);            // 4 KB overlay ring[0]

    const int isf32 = *flagp;
    const int tid  = threadIdx.x;
    const int lane = tid & 63;
    const int wave = tid >> 6;        // 0..7
    const int bx   = blockIdx.x;
    const int i    = bx >> 1;         // 0..255
    const int jh   = bx & 1;          // j-half
    const int jq   = wave & 1;        // j quarter within half (64 rows)
    const int ms   = wave >> 1;       // m eighth (128 cols)  0..3
    const int l31  = lane & 31;
    const int lhi  = lane >> 5;

    // ---- stage Ws: 128 j-rows x 32 k-units -> [ku][jrow] bf16 (64 KB) ----
#pragma unroll
    for (int p = 0; p < 8; ++p) {
        const int u = tid + p*512;
        const int jrow = u >> 5, cu = u & 31;
        F8 f = load8(wc, (i*HH + jh*128 + jrow)*HH + cu*8, isf32);
        unsigned short tmp[8];
#pragma unroll
        for (int j = 0; j < 8; ++j) tmp[j] = f2bf(f.v[j]);
        *(uint4*)(Ws + (cu*128 + jrow)*8) = *(const uint4*)tmp;
    }
    // drain own ds_writes so the first raw barrier publishes Ws
    asm volatile("s_waitcnt lgkmcnt(0)" ::: "memory");

    // DMA roles: chunk = [4 ku][512 m] (BK=32), 32 KB. Thread tid covers
    // mrow=tid at ku=p (p=0..3): 4 gload16/chunk. LDS elem (p*512+tid)*8;
    // wave-uniform base = (p*512 + (tid&~63))*8, HW adds lane*16.
    const unsigned short* gbase = ctx_hist + (size_t)tid*HH;
    const int wu = (tid & ~63)*8;

    // fragment bases
    const int wbase = (jq*64 + l31)*8;             // Ws: + ku*1024 (+256 a=1)
    const int bofs  = (ms*128 + l31)*8;            // ring: + kuL*4096 + n*256

#pragma unroll 1
    for (int mc = 0; mc < 4; ++mc) {
        const unsigned short* gm = gbase + (size_t)(mc*512)*HH;

        // ---- acc init = bc[j] broadcast across m (all n) ----
        f32x16 acc[2][4];
#pragma unroll
        for (int a = 0; a < 2; ++a)
#pragma unroll
            for (int g = 0; g < 4; ++g) {
                const int jb = i*HH + jh*128 + jq*64 + a*32 + g*8 + lhi*4;
                float b0, b1, b2, b3;
                if (isf32) {
                    float4 t = *(const float4*)((const float*)bc + jb);
                    b0 = t.x; b1 = t.y; b2 = t.z; b3 = t.w;
                } else {
                    ushort4 t = *(const ushort4*)((const unsigned short*)bc + jb);
                    b0 = bf2f(t.x); b1 = bf2f(t.y); b2 = bf2f(t.z); b3 = bf2f(t.w);
                }
#pragma unroll
                for (int n = 0; n < 4; ++n) {
                    acc[a][n][g*4+0] = b0;
                    acc[a][n][g*4+1] = b1;
                    acc[a][n][g*4+2] = b2;
                    acc[a][n][g*4+3] = b3;
                }
            }

        // ---- prologue: issue chunks 0,1 into ring[0],ring[1] ----
#pragma unroll
        for (int c = 0; c < 2; ++c)
#pragma unroll
            for (int p = 0; p < 4; ++p)
                gload16(gm + c*32 + p*8, ring + c*16384 + p*4096 + wu);

        // ---- 8 phases, counted vmcnt, raw barriers ----
#pragma unroll
        for (int kc = 0; kc < 8; ++kc) {
            if (kc < 7) asm volatile("s_waitcnt vmcnt(4)" ::: "memory");
            else        asm volatile("s_waitcnt vmcnt(0)" ::: "memory");
            __builtin_amdgcn_s_barrier();
            if (kc < 6) {
                const int c = kc + 2, rb = c % 3;
#pragma unroll
                for (int p = 0; p < 4; ++p)
                    gload16(gm + c*32 + p*8, ring + rb*16384 + p*4096 + wu);
            }
            const unsigned short* Ac = ring + (kc % 3)*16384;
#pragma unroll
            for (int ks = 0; ks < 2; ++ks) {
                const int kuW = kc*4 + ks*2 + lhi;          // 0..31
                const int kuL = ks*2 + lhi;                 // 0..3
                bf16x8 w0 = *(const bf16x8*)(Ws + kuW*1024 + wbase);
                bf16x8 w1 = *(const bf16x8*)(Ws + kuW*1024 + wbase + 256);
                bf16x8 b0 = *(const bf16x8*)(Ac + kuL*4096 + bofs);
                bf16x8 b1 = *(const bf16x8*)(Ac + kuL*4096 + bofs + 256);
                bf16x8 b2 = *(const bf16x8*)(Ac + kuL*4096 + bofs + 512);
                bf16x8 b3 = *(const bf16x8*)(Ac + kuL*4096 + bofs + 768);
                __builtin_amdgcn_s_setprio(1);
                acc[0][0] = __builtin_amdgcn_mfma_f32_32x32x16_bf16(w0, b0, acc[0][0], 0, 0, 0);
                acc[0][1] = __builtin_amdgcn_mfma_f32_32x32x16_bf16(w0, b1, acc[0][1], 0, 0, 0);
                acc[0][2] = __builtin_amdgcn_mfma_f32_32x32x16_bf16(w0, b2, acc[0][2], 0, 0, 0);
                acc[0][3] = __builtin_amdgcn_mfma_f32_32x32x16_bf16(w0, b3, acc[0][3], 0, 0, 0);
                acc[1][0] = __builtin_amdgcn_mfma_f32_32x32x16_bf16(w1, b0, acc[1][0], 0, 0, 0);
                acc[1][1] = __builtin_amdgcn_mfma_f32_32x32x16_bf16(w1, b1, acc[1][1], 0, 0, 0);
                acc[1][2] = __builtin_amdgcn_mfma_f32_32x32x16_bf16(w1, b2, acc[1][2], 0, 0, 0);
                acc[1][3] = __builtin_amdgcn_mfma_f32_32x32x16_bf16(w1, b3, acc[1][3], 0, 0, 0);
                __builtin_amdgcn_s_setprio(0);
            }
        }

        // ---- lean epilogue: partial[m] = sum_j acc[j,m] * ipT[j][m] ----
        const unsigned short* pb =
            ipT + (size_t)(jh*128 + jq*64 + lhi*4)*MM + (mc*512 + ms*128 + l31);
        float sv[4];
#pragma unroll
        for (int n = 0; n < 4; ++n) {
            float s = 0.0f;
#pragma unroll
            for (int a = 0; a < 2; ++a)
#pragma unroll
                for (int g = 0; g < 4; ++g) {
                    const unsigned short* prow = pb + (size_t)(a*32 + g*8)*MM + n*32;
#pragma unroll
                    for (int q = 0; q < 4; ++q)
                        s = fmaf(acc[a][n][g*4+q], bf2f(prow[(size_t)q*MM]), s);
                }
            s += __shfl_xor(s, 32);   // combine lhi halves (same m column)
            sv[n] = s;
        }
        // Ps overlays ring[0]: all DMA drained (phase 7 vmcnt(0)); ring[0]'s
        // last reader (chunk 6, phase 6) is ordered by phase 7's barrier.
        if (lhi == 0) {
#pragma unroll
            for (int n = 0; n < 4; ++n)
                Ps[jq*512 + ms*128 + n*32 + l31] = sv[n];
        }
        __syncthreads();
        atomicAdd(&outT[(size_t)i*MM + mc*512 + tid], Ps[tid] + Ps[512+tid]);
        __syncthreads();   // Ps reads done before next mc's prologue DMA
    }
}

// ---------------------------------------------------------------------------
// K4: transpose outT[256 i][2048 m] f32 -> out[m][i] (+ hidden dup region).
// ---------------------------------------------------------------------------
__global__ __launch_bounds__(256) void k4_tr(
    const float* __restrict__ outT,
    const int* __restrict__ flagp,
    void* __restrict__ out)
{
    const int isf32 = *flagp;
    __shared__ float tile[64][65];
    const int t  = threadIdx.x;
    const int bm = blockIdx.x * 64;   // m base
    const int bi = blockIdx.y * 64;   // i base
#pragma unroll
    for (int p = 0; p < 16; ++p) {
        const int u = t + p*256;
        const int r = u >> 6, c = u & 63;          // r = i offset, c = m offset
        tile[r][c] = outT[(size_t)(bi + r)*MM + bm + c];
    }
    __syncthreads();
#pragma unroll
    for (int p = 0; p < 16; ++p) {
        const int u = t + p*256;
        const int r = u >> 6, c = u & 63;          // r = m offset, c = i offset
        const float v = tile[c][r];
        const int m = bm + r;
        if (isf32) {
            float* o = (float*)out;
            o[(size_t)m*HH + bi + c] = v;
            if (m >= MM - BB) o[(size_t)MM*HH + (m - (MM-BB))*HH + bi + c] = v;
        } else {
            unsigned short* o = (unsigned short*)out;
            const unsigned short vb = f2bf(v);
            o[(size_t)m*HH + bi + c] = vb;
            if (m >= MM - BB) o[(size_t)MM*HH + (m - (MM-BB))*HH + bi + c] = vb;
        }
    }
}

// ---------------------------------------------------------------------------
extern "C" void kernel_launch(void* const* d_in, const int* in_sizes, int n_in,
                              void* d_out, int out_size, void* d_ws, size_t ws_size,
                              hipStream_t stream) {
    const void* x     = d_in[0];
    const void* w_i2h = d_in[1];
    const void* b_i2h = d_in[2];
    // d_in[3]=w_h2h, d_in[4]=b_h2h: dead code (reference overwrites hidden=transformed)
    const void* w_i2c = d_in[5];
    const void* b_i2c = d_in[6];
    const void* w_c2c = d_in[7];
    const void* b_c2c = d_in[8];
    const void* w_c2t = d_in[9];
    const void* b_c2t = d_in[10];
    const int* ns     = (const int*)d_in[11];

    // ws layout: ipT bf16 [256,2048] | ctx_hist bf16 [2048,256] |
    //            cin f32 [2048,256] (reused as outT f32 [256,2048]) | flag int
    unsigned short* ipT = (unsigned short*)d_ws;
    unsigned short* ch  = (unsigned short*)((char*)d_ws + (size_t)MM*HH*2);
    float* cin          = (float*)((char*)d_ws + (size_t)MM*HH*4);
    float* outT         = cin;   // k2 consumes cin before k25 zeroes / k3 adds
    int* flag           = (int*)((char*)d_ws + (size_t)MM*HH*8);

    // allow 160 KiB dynamic LDS for k3 (host-side attribute; capture-safe)
    (void)hipFuncSetAttribute((const void*)k3_main,
                              hipFuncAttributeMaxDynamicSharedMemorySize, 163840);

    k0_sniff<<<1, 256, 0, stream>>>((const unsigned short*)x, flag);
    k1_proj<<<64, 256, 0, stream>>>(x, w_i2h, b_i2h, w_i2c, b_i2c, flag, ipT, cin);
    k2_ctx<<<BB, 256, 0, stream>>>(w_c2c, b_c2c, cin, ns, flag, ch, d_out);
    k25_zero<<<512, 256, 0, stream>>>(outT);
    k3_main<<<512, 512, 163840, stream>>>(ch, w_c2t, b_c2t, ipT, flag, outT);
    k4_tr<<<dim3(32, 4), 256, 0, stream>>>(outT, flag, d_out);
}

// Round 10
// 326.793 us; speedup vs baseline: 1.1037x; 1.1037x over previous
//
#include <hip/hip_runtime.h>

// Problem constants (T=64, B=32, I=128, H=256, alpha=0.2)
#define TT 64
#define BB 32
#define II 128
#define HH 256
#define MM (TT*BB)   // 2048

typedef __bf16  bf16x8  __attribute__((ext_vector_type(8)));
typedef float   f32x16  __attribute__((ext_vector_type(16)));
typedef _Float16 half2v __attribute__((ext_vector_type(2)));
typedef unsigned int u32;

__device__ __forceinline__ float bf2f(unsigned short u) {
    union { unsigned int i; float f; } v; v.i = ((unsigned int)u) << 16; return v.f;
}
__device__ __forceinline__ unsigned short f2bf(float f) {
    union { float f; unsigned int i; } v; v.f = f;
    unsigned int r = v.i + 0x7fffu + ((v.i >> 16) & 1u);
    return (unsigned short)(r >> 16);
}

// async 16B HBM->LDS copy, no destination VGPR. LDS base must be wave-uniform;
// hardware writes base + lane*16.
__device__ __forceinline__ void gload16(const unsigned short* g, unsigned short* l) {
    __builtin_amdgcn_global_load_lds(
        (const __attribute__((address_space(1))) u32*)g,
        (__attribute__((address_space(3))) u32*)l,
        16, 0, 0);
}

// Dual-dtype loaders: external tensors may be fp32 or bf16; runtime flag decides.
struct F8 { float v[8]; };
__device__ __forceinline__ F8 load8(const void* base, int idx, int isf32) {
    F8 r;
    if (isf32) {
        const float4* p = (const float4*)((const float*)base + idx);
        float4 a = p[0], b = p[1];
        r.v[0]=a.x; r.v[1]=a.y; r.v[2]=a.z; r.v[3]=a.w;
        r.v[4]=b.x; r.v[5]=b.y; r.v[6]=b.z; r.v[7]=b.w;
    } else {
        uint4 u = *(const uint4*)((const unsigned short*)base + idx);
        const unsigned short* p = (const unsigned short*)&u;
#pragma unroll
        for (int j = 0; j < 8; ++j) r.v[j] = bf2f(p[j]);
    }
    return r;
}
__device__ __forceinline__ float load1(const void* base, int idx, int isf32) {
    return isf32 ? ((const float*)base)[idx]
                 : bf2f(((const unsigned short*)base)[idx]);
}

__device__ __forceinline__ float fdot2f(half2v a, half2v b, float c) {
#if __has_builtin(__builtin_amdgcn_fdot2)
    return __builtin_amdgcn_fdot2(a, b, c, false);
#else
    return c + (float)a.x*(float)b.x + (float)a.y*(float)b.y;
#endif
}

// ---------------------------------------------------------------------------
// K1 v4: self-sniffing (k0 eliminated). Each block scans x's first 8192
// ushorts (identical logic to the old k0); block 0 publishes the flag for
// downstream kernels. Then: weights in VGPRs, 32 m per block, emits
// ipT[j][m] via LDS transpose + cin (unchanged from v3).
// ---------------------------------------------------------------------------
__global__ __launch_bounds__(256) void k1_proj(
    const void* __restrict__ x,
    const void* __restrict__ w_i2h,
    const void* __restrict__ b_i2h,
    const void* __restrict__ w_i2c,
    const void* __restrict__ b_i2c,
    int* __restrict__ flagp,                    // OUT: dtype flag
    unsigned short* __restrict__ ipT,
    float* __restrict__ cin)
{
    const int tid = threadIdx.x;
    const int h = tid;
    const int mbase = blockIdx.x * 32;
    __shared__ __align__(16) _Float16 xs[32][II];          // 8 KB
    __shared__ __align__(16) unsigned short ips[32][HH];   // 16 KB
    __shared__ int cnt;

    // ---- self-sniff (was k0): fp32 read as ushorts -> ~25% exp >= 0xC0 ----
    if (tid == 0) cnt = 0;
    __syncthreads();
    {
        const unsigned short* xu = (const unsigned short*)x;
        int c = 0;
        for (int idx = tid; idx < 8192; idx += 256) {
            unsigned int e = (xu[idx] >> 7) & 0xFFu;
            if (e >= 0xC0u) ++c;
        }
        atomicAdd(&cnt, c);
    }
    __syncthreads();
    const int isf32 = (cnt > 16) ? 1 : 0;
    if (blockIdx.x == 0 && tid == 0) flagp[0] = isf32;

    half2v w1[II/2], w2[II/2];
#pragma unroll
    for (int c8 = 0; c8 < II/8; ++c8) {
        F8 f1 = load8(w_i2h, h*II + c8*8, isf32);
        F8 f2 = load8(w_i2c, h*II + c8*8, isf32);
#pragma unroll
        for (int j = 0; j < 4; ++j) {
            half2v a; a.x = (_Float16)f1.v[2*j]; a.y = (_Float16)f1.v[2*j+1];
            half2v b; b.x = (_Float16)f2.v[2*j]; b.y = (_Float16)f2.v[2*j+1];
            w1[c8*4 + j] = a;
            w2[c8*4 + j] = b;
        }
    }
    const float bb1 = load1(b_i2h, h, isf32);
    const float bb2 = load1(b_i2c, h, isf32);

    for (int u = tid; u < 32*II; u += 256)
        xs[u >> 7][u & (II-1)] = (_Float16)load1(x, (mbase + (u >> 7))*II + (u & (II-1)), isf32);
    __syncthreads();

    for (int mm = 0; mm < 32; ++mm) {
        const half2v* xv = (const half2v*)xs[mm];
        float a0=0,a1=0,a2=0,a3=0, c0=0,c1=0,c2=0,c3=0;
#pragma unroll
        for (int r = 0; r < II/2; r += 4) {
            half2v x0 = xv[r], x1 = xv[r+1], x2 = xv[r+2], x3 = xv[r+3];
            a0 = fdot2f(w1[r],   x0, a0);
            a1 = fdot2f(w1[r+1], x1, a1);
            a2 = fdot2f(w1[r+2], x2, a2);
            a3 = fdot2f(w1[r+3], x3, a3);
            c0 = fdot2f(w2[r],   x0, c0);
            c1 = fdot2f(w2[r+1], x1, c1);
            c2 = fdot2f(w2[r+2], x2, c2);
            c3 = fdot2f(w2[r+3], x3, c3);
        }
        ips[mm][h] = f2bf(((a0+a1)+(a2+a3)) + bb1);
        cin[(mbase+mm)*HH + h] = ((c0+c1)+(c2+c3)) + bb2;
    }
    __syncthreads();
    unsigned short tmp[32];
#pragma unroll
    for (int mm = 0; mm < 32; ++mm) tmp[mm] = ips[mm][tid];
    uint4* dst = (uint4*)(ipT + (size_t)tid*MM + mbase);
    const uint4* s4 = (const uint4*)tmp;
    dst[0] = s4[0]; dst[1] = s4[1]; dst[2] = s4[2]; dst[3] = s4[3];
}

// ---------------------------------------------------------------------------
// K2 (unchanged): per-sample context chains, double-buffered LDS.
// ---------------------------------------------------------------------------
__global__ __launch_bounds__(256) void k2_ctx(
    const void* __restrict__ w_c2c,
    const void* __restrict__ b_c2c,
    const float* __restrict__ cin,
    const int* __restrict__ ns_ptr,
    const int* __restrict__ flagp,
    unsigned short* __restrict__ ctx_hist,
    void* __restrict__ out_base)
{
    const int isf32 = *flagp;
    const int b = blockIdx.x;
    const int h = threadIdx.x;
    const int ns = max(1, *ns_ptr);

    __shared__ __align__(16) _Float16 cs[2][HH];

    half2v w[HH/2];
#pragma unroll
    for (int c8 = 0; c8 < HH/8; ++c8) {
        F8 f = load8(w_c2c, h*HH + c8*8, isf32);
#pragma unroll
        for (int j = 0; j < 4; ++j) {
            half2v hv;
            hv.x = (_Float16)f.v[2*j];
            hv.y = (_Float16)f.v[2*j+1];
            w[c8*4 + j] = hv;
        }
    }
    const float bcc = load1(b_c2c, h, isf32);
    float ctxv = 0.0f;
    cs[0][h] = (_Float16)0.0f;
    __syncthreads();
    int cur = 0;

    for (int t = 0; t < TT; ++t) {
        const float cinv = cin[(t*BB + b)*HH + h];
        for (int s = 0; s < ns; ++s) {
            if (s == ns-1) ctx_hist[(t*BB + b)*HH + h] = f2bf(ctxv);
            float p0=0,p1=0,p2=0,p3=0;
            const float4* cp4 = (const float4*)cs[cur];
#pragma unroll
            for (int r4 = 0; r4 < HH/8; ++r4) {
                float4 blob = cp4[r4];
                const half2v* c2 = (const half2v*)&blob;
                p0 = fdot2f(w[r4*4+0], c2[0], p0);
                p1 = fdot2f(w[r4*4+1], c2[1], p1);
                p2 = fdot2f(w[r4*4+2], c2[2], p2);
                p3 = fdot2f(w[r4*4+3], c2[3], p3);
            }
            float cnew = fmaxf(((p0+p1)+(p2+p3)) + bcc + cinv, 0.0f);
            ctxv = 0.8f*ctxv + 0.2f*cnew;
            cs[cur^1][h] = (_Float16)ctxv;
            cur ^= 1;
            __syncthreads();
        }
    }
    const int cofs = MM*HH + BB*HH + b*HH + h;
    if (isf32) ((float*)out_base)[cofs] = ctxv;
    else       ((unsigned short*)out_base)[cofs] = f2bf(ctxv);
}

// ---------------------------------------------------------------------------
// K25: zero outT (2 MB) before k3's atomic accumulation. (Cannot merge into
// k2: outT aliases cin, which other k2 blocks still read until k2 ends.)
// ---------------------------------------------------------------------------
__global__ __launch_bounds__(256) void k25_zero(float* __restrict__ outT)
{
    const int idx = (blockIdx.x * 256 + threadIdx.x) * 4;
    *(float4*)(outT + idx) = make_float4(0.f, 0.f, 0.f, 0.f);
}

// ---------------------------------------------------------------------------
// K3 v10 (byte-exact revert to the 143-us best): 8-phase counted-vmcnt
// pipeline (T3+T4), grid 512 = i x j-half, 8 waves = 2jq x 4ms, acc[2][2].
//  * LDS 128 KB: Ws [32 ku][128 j] resident (64 KB, conflict-free) +
//    4-buffer ring of [4 ku][256 m] BK=32 ctx chunks (4 x 16 KB).
//  * DMA issued 3 chunks ahead; each phase: vmcnt(4|2|0-tail) -> raw
//    s_barrier -> issue chunk kc+3 -> 8 ds_read_b128 + 8 MFMA (setprio).
//    No vmcnt(0) drain in the steady loop.
//  * bc folded into acc init; lean epilogue + Ps overlay + atomicAdd.
// (v11's fat-acc variant regressed 143->172: reverted.)
// ---------------------------------------------------------------------------
__global__ __launch_bounds__(512, 2) void k3_main(
    const unsigned short* __restrict__ ctx_hist,  // [2048 m,256 k] bf16 (internal)
    const void* __restrict__ wc,                  // [65536,256] external
    const void* __restrict__ bc,                  // [65536]     external
    const unsigned short* __restrict__ ipT,       // [256 j][2048 m] bf16 (internal)
    const int* __restrict__ flagp,
    float* __restrict__ outT)                     // [256 i][2048 m] f32 (internal)
{
    extern __shared__ __align__(16) unsigned char lds[];
    unsigned short* Ws   = (unsigned short*)lds;             // 65536 B [ku][jrow]
    unsigned short* ring = (unsigned short*)(lds + 65536);   // 4 x 16384 B
    float*          Ps   = (float*)(lds + 65536);            // 2 KB overlay ring[0]

    const int isf32 = *flagp;
    const int tid  = threadIdx.x;
    const int lane = tid & 63;
    const int wave = tid >> 6;        // 0..7
    const int bx   = blockIdx.x;
    const int i    = bx >> 1;         // 0..255
    const int jh   = bx & 1;          // j-half
    const int jq   = wave & 1;        // j quarter within half (64 rows)
    const int ms   = wave >> 1;       // m quarter (64 cols)
    const int l31  = lane & 31;
    const int lhi  = lane >> 5;

    // ---- stage Ws: 128 j-rows x 32 k-units -> [ku][jrow] bf16 (64 KB) ----
#pragma unroll
    for (int p = 0; p < 8; ++p) {
        const int u = tid + p*512;
        const int jrow = u >> 5, cu = u & 31;
        F8 f = load8(wc, (i*HH + jh*128 + jrow)*HH + cu*8, isf32);
        unsigned short tmp[8];
#pragma unroll
        for (int j = 0; j < 8; ++j) tmp[j] = f2bf(f.v[j]);
        *(uint4*)(Ws + (cu*128 + jrow)*8) = *(const uint4*)tmp;
    }
    // drain own ds_writes so the first raw barrier publishes Ws
    asm volatile("s_waitcnt lgkmcnt(0)" ::: "memory");

    // DMA roles: chunk = [4 ku][256 m] (BK=32). Per thread 2 issues:
    // unit u = wave*128 + p*64 + lane; mrow = u&255, ku4 = u>>8.
    // LDS base (wave-uniform) = ring + rb*8192 + (wave*128 + p*64)*8.
    const int u0 = wave*128 + lane;          // p=0 unit
    const int m0row = u0 & 255, k0u = u0 >> 8;
    const int u1 = u0 + 64;                  // p=1 unit
    const int m1row = u1 & 255, k1u = u1 >> 8;
    const int wb0 = (wave*128)*8;            // uniform elems
    const int wb1 = (wave*128 + 64)*8;

    // fragment bases
    const int wbase = (jq*64 + l31)*8;                 // Ws: + ku*1024 (+256 for a=1)
    const int bofs  = (lhi*256 + ms*64 + l31)*8;       // ring: + ks*4096 (+256 for n=1)

#pragma unroll 1
    for (int mc = 0; mc < 8; ++mc) {
        const unsigned short* gm = ctx_hist + (size_t)(mc*256)*HH;

        // ---- acc init = bc[j] broadcast across m ----
        f32x16 acc[2][2];
#pragma unroll
        for (int a = 0; a < 2; ++a)
#pragma unroll
            for (int g = 0; g < 4; ++g) {
                const int jb = i*HH + jh*128 + jq*64 + a*32 + g*8 + lhi*4;
                float b0, b1, b2, b3;
                if (isf32) {
                    float4 t = *(const float4*)((const float*)bc + jb);
                    b0 = t.x; b1 = t.y; b2 = t.z; b3 = t.w;
                } else {
                    ushort4 t = *(const ushort4*)((const unsigned short*)bc + jb);
                    b0 = bf2f(t.x); b1 = bf2f(t.y); b2 = bf2f(t.z); b3 = bf2f(t.w);
                }
                acc[a][0][g*4+0] = b0; acc[a][1][g*4+0] = b0;
                acc[a][0][g*4+1] = b1; acc[a][1][g*4+1] = b1;
                acc[a][0][g*4+2] = b2; acc[a][1][g*4+2] = b2;
                acc[a][0][g*4+3] = b3; acc[a][1][g*4+3] = b3;
            }

        // ---- prologue: issue chunks 0..2 into ring[0..2] ----
#pragma unroll
        for (int c = 0; c < 3; ++c) {
            gload16(gm + m0row*HH + c*32 + k0u*8, ring + c*8192 + wb0);
            gload16(gm + m1row*HH + c*32 + k1u*8, ring + c*8192 + wb1);
        }

        // ---- 8 phases, counted vmcnt, raw barriers ----
#pragma unroll
        for (int kc = 0; kc < 8; ++kc) {
            if (kc < 6)       asm volatile("s_waitcnt vmcnt(4)" ::: "memory");
            else if (kc == 6) asm volatile("s_waitcnt vmcnt(2)" ::: "memory");
            else              asm volatile("s_waitcnt vmcnt(0)" ::: "memory");
            __builtin_amdgcn_s_barrier();
            if (kc < 5) {
                const int c = kc + 3, rb = c & 3;
                gload16(gm + m0row*HH + c*32 + k0u*8, ring + rb*8192 + wb0);
                gload16(gm + m1row*HH + c*32 + k1u*8, ring + rb*8192 + wb1);
            }
            const unsigned short* Ac = ring + (kc & 3)*8192;
#pragma unroll
            for (int ks = 0; ks < 2; ++ks) {
                const int ku = kc*4 + ks*2 + lhi;          // 0..31
                bf16x8 w0 = *(const bf16x8*)(Ws + ku*1024 + wbase);
                bf16x8 w1 = *(const bf16x8*)(Ws + ku*1024 + wbase + 256);
                bf16x8 b0 = *(const bf16x8*)(Ac + bofs + ks*4096);
                bf16x8 b1 = *(const bf16x8*)(Ac + bofs + ks*4096 + 256);
                __builtin_amdgcn_s_setprio(1);
                acc[0][0] = __builtin_amdgcn_mfma_f32_32x32x16_bf16(w0, b0, acc[0][0], 0, 0, 0);
                acc[0][1] = __builtin_amdgcn_mfma_f32_32x32x16_bf16(w0, b1, acc[0][1], 0, 0, 0);
                acc[1][0] = __builtin_amdgcn_mfma_f32_32x32x16_bf16(w1, b0, acc[1][0], 0, 0, 0);
                acc[1][1] = __builtin_amdgcn_mfma_f32_32x32x16_bf16(w1, b1, acc[1][1], 0, 0, 0);
                __builtin_amdgcn_s_setprio(0);
            }
        }

        // ---- lean epilogue: partial[m] = sum_j acc[j,m] * ipT[j][m] ----
        float sv0 = 0.0f, sv1 = 0.0f;
        const int mcol = mc*256 + ms*64 + l31;
#pragma unroll
        for (int a = 0; a < 2; ++a)
#pragma unroll
            for (int g = 0; g < 4; ++g) {
                const unsigned short* prow =
                    ipT + (jh*128 + jq*64 + a*32 + g*8 + lhi*4)*MM + mcol;
#pragma unroll
                for (int q = 0; q < 4; ++q) {
                    sv0 = fmaf(acc[a][0][g*4+q], bf2f(prow[q*MM]),      sv0);
                    sv1 = fmaf(acc[a][1][g*4+q], bf2f(prow[q*MM + 32]), sv1);
                }
            }
        sv0 += __shfl_xor(sv0, 32);   // combine lhi halves (same m column)
        sv1 += __shfl_xor(sv1, 32);
        // Ps overlays ring[0]: all DMA drained (phase 7 vmcnt(0)); ring[0]'s
        // last reader (chunk 4, phase 4) is ordered by phases 5-7 barriers.
        if (lhi == 0) {
            Ps[jq*256 + ms*64 +      l31] = sv0;
            Ps[jq*256 + ms*64 + 32 + l31] = sv1;
        }
        __syncthreads();
        if (tid < 256)
            atomicAdd(&outT[(size_t)i*MM + mc*256 + tid], Ps[tid] + Ps[256+tid]);
        __syncthreads();   // Ps reads done before next mc's prologue DMA
    }
}

// ---------------------------------------------------------------------------
// K4: transpose outT[256 i][2048 m] f32 -> out[m][i] (+ hidden dup region).
// ---------------------------------------------------------------------------
__global__ __launch_bounds__(256) void k4_tr(
    const float* __restrict__ outT,
    const int* __restrict__ flagp,
    void* __restrict__ out)
{
    const int isf32 = *flagp;
    __shared__ float tile[64][65];
    const int t  = threadIdx.x;
    const int bm = blockIdx.x * 64;   // m base
    const int bi = blockIdx.y * 64;   // i base
#pragma unroll
    for (int p = 0; p < 16; ++p) {
        const int u = t + p*256;
        const int r = u >> 6, c = u & 63;          // r = i offset, c = m offset
        tile[r][c] = outT[(size_t)(bi + r)*MM + bm + c];
    }
    __syncthreads();
#pragma unroll
    for (int p = 0; p < 16; ++p) {
        const int u = t + p*256;
        const int r = u >> 6, c = u & 63;          // r = m offset, c = i offset
        const float v = tile[c][r];
        const int m = bm + r;
        if (isf32) {
            float* o = (float*)out;
            o[(size_t)m*HH + bi + c] = v;
            if (m >= MM - BB) o[(size_t)MM*HH + (m - (MM-BB))*HH + bi + c] = v;
        } else {
            unsigned short* o = (unsigned short*)out;
            const unsigned short vb = f2bf(v);
            o[(size_t)m*HH + bi + c] = vb;
            if (m >= MM - BB) o[(size_t)MM*HH + (m - (MM-BB))*HH + bi + c] = vb;
        }
    }
}

// ---------------------------------------------------------------------------
extern "C" void kernel_launch(void* const* d_in, const int* in_sizes, int n_in,
                              void* d_out, int out_size, void* d_ws, size_t ws_size,
                              hipStream_t stream) {
    const void* x     = d_in[0];
    const void* w_i2h = d_in[1];
    const void* b_i2h = d_in[2];
    // d_in[3]=w_h2h, d_in[4]=b_h2h: dead code (reference overwrites hidden=transformed)
    const void* w_i2c = d_in[5];
    const void* b_i2c = d_in[6];
    const void* w_c2c = d_in[7];
    const void* b_c2c = d_in[8];
    const void* w_c2t = d_in[9];
    const void* b_c2t = d_in[10];
    const int* ns     = (const int*)d_in[11];

    // ws layout: ipT bf16 [256,2048] | ctx_hist bf16 [2048,256] |
    //            cin f32 [2048,256] (reused as outT f32 [256,2048]) | flag int
    unsigned short* ipT = (unsigned short*)d_ws;
    unsigned short* ch  = (unsigned short*)((char*)d_ws + (size_t)MM*HH*2);
    float* cin          = (float*)((char*)d_ws + (size_t)MM*HH*4);
    float* outT         = cin;   // k2 consumes cin before k25 zeroes / k3 adds
    int* flag           = (int*)((char*)d_ws + (size_t)MM*HH*8);

    // allow 128 KiB dynamic LDS for k3 (host-side attribute; capture-safe)
    (void)hipFuncSetAttribute((const void*)k3_main,
                              hipFuncAttributeMaxDynamicSharedMemorySize, 131072);

    k1_proj<<<64, 256, 0, stream>>>(x, w_i2h, b_i2h, w_i2c, b_i2c, flag, ipT, cin);
    k2_ctx<<<BB, 256, 0, stream>>>(w_c2c, b_c2c, cin, ns, flag, ch, d_out);
    k25_zero<<<512, 256, 0, stream>>>(outT);
    k3_main<<<512, 512, 131072, stream>>>(ch, w_c2t, b_c2t, ipT, flag, outT);
    k4_tr<<<dim3(32, 4), 256, 0, stream>>>(outT, flag, d_out);
}